// Round 2
// baseline (295.163 us; speedup 1.0000x reference)
//
#include <hip/hip_runtime.h>

typedef _Float16 f16;
typedef _Float16 f16x8 __attribute__((ext_vector_type(8)));
typedef _Float16 f16x4 __attribute__((ext_vector_type(4)));
typedef float    f32x4 __attribute__((ext_vector_type(4)));
typedef unsigned int u32t;

#define AS1 __attribute__((address_space(1)))
#define AS3 __attribute__((address_space(3)))

static __device__ __forceinline__ void gload_lds16(const void* g, void* l) {
  __builtin_amdgcn_global_load_lds((const AS1 u32t*)g, (AS3 u32t*)l, 16, 0, 0);
}

static __device__ __forceinline__ f16x8 zero8() {
  f16x8 z;
#pragma unroll
  for (int j = 0; j < 8; ++j) z[j] = (f16)0;
  return z;
}

// ---------------- convert x (fp32 -> fp16) ----------------
__global__ void k_cvt_x(const float* __restrict__ in, f16* __restrict__ out, int n4) {
  int stride = gridDim.x * blockDim.x;
  for (int i = blockIdx.x * blockDim.x + threadIdx.x; i < n4; i += stride) {
    float4 v = ((const float4*)in)[i];
    f16x4 o;
    o[0] = (f16)v.x; o[1] = (f16)v.y; o[2] = (f16)v.z; o[3] = (f16)v.w;
    ((f16x4*)out)[i] = o;
  }
}

// ---------------- convert + transpose W: [1280][N] f32 -> [N][1280] f16 ----------------
__global__ void k_cvt_w_t(const float* __restrict__ W, f16* __restrict__ Wt, int N) {
  __shared__ float T[32][33];
  int bk = blockIdx.x % 40;          // 1280/32
  int bn = blockIdx.x / 40;
  int k0 = bk * 32, n0 = bn * 32;
  int r = threadIdx.x >> 5;          // 0..7
  int c = threadIdx.x & 31;
#pragma unroll
  for (int i = 0; i < 4; ++i)
    T[r + i * 8][c] = W[(size_t)(k0 + r + i * 8) * N + n0 + c];
  __syncthreads();
#pragma unroll
  for (int i = 0; i < 4; ++i)
    Wt[(size_t)(n0 + r + i * 8) * 1280 + k0 + c] = (f16)T[c][r + i * 8];
}

// ================= 256x256-tile GEMM, BK=32, 4-buffer LDS ring =================
// C[M=8192, NCOLS] = A[8192,1280] * Bt[NCOLS,1280]^T + bias
// 512 threads = 8 waves (2 M x 4 N); per-wave output 128x64 (8 m-frags x 4 n-frags).
// LDS: A ring 4x16KB @0, B ring 4x16KB @65536. Tile t -> buf t&3.
// Prefetch distance 3 tiles; steady-state vmcnt(8); ONE s_barrier per K-tile.
// K-tile [256 rows][32 k] f16 row-major (64B rows): frag reads are contiguous
// 1KB blocks -> bank-conflict-free, staging is linear (global_load_lds OK).

template<int VM, bool STAGE>
static __device__ __forceinline__ void ktile(
    int t, int ts_buf,
    const char* const (&gA)[2], const char* const (&gB)[2],
    char* const (&dA)[2], char* const (&dB)[2],
    char* bA, char* bB,
    const int (&offA)[8], const int (&offB)[4], f32x4 (&acc)[8][4])
{
  if constexpr (STAGE) {
    const long ko = (long)(t + 3) * 64;
#pragma unroll
    for (int l = 0; l < 2; ++l) gload_lds16(gA[l] + ko, dA[l] + ts_buf * 16384);
  }
  f16x8 af[8];
#pragma unroll
  for (int f = 0; f < 8; ++f) af[f] = *(const f16x8*)(bA + offA[f]);
  f16x8 b0 = *(const f16x8*)(bB + offB[0]);
  f16x8 b1 = *(const f16x8*)(bB + offB[1]);
  __builtin_amdgcn_s_setprio(1);
#pragma unroll
  for (int f = 0; f < 8; ++f)
    acc[f][0] = __builtin_amdgcn_mfma_f32_16x16x32_f16(af[f], b0, acc[f][0], 0, 0, 0);
#pragma unroll
  for (int f = 0; f < 8; ++f)
    acc[f][1] = __builtin_amdgcn_mfma_f32_16x16x32_f16(af[f], b1, acc[f][1], 0, 0, 0);
  __builtin_amdgcn_s_setprio(0);
  if constexpr (STAGE) {
    const long ko = (long)(t + 3) * 64;
#pragma unroll
    for (int l = 0; l < 2; ++l) gload_lds16(gB[l] + ko, dB[l] + ts_buf * 16384);
  }
  f16x8 b2 = *(const f16x8*)(bB + offB[2]);
  f16x8 b3 = *(const f16x8*)(bB + offB[3]);
  __builtin_amdgcn_s_setprio(1);
#pragma unroll
  for (int f = 0; f < 8; ++f)
    acc[f][2] = __builtin_amdgcn_mfma_f32_16x16x32_f16(af[f], b2, acc[f][2], 0, 0, 0);
#pragma unroll
  for (int f = 0; f < 8; ++f)
    acc[f][3] = __builtin_amdgcn_mfma_f32_16x16x32_f16(af[f], b3, acc[f][3], 0, 0, 0);
  __builtin_amdgcn_s_setprio(0);
  if constexpr (VM >= 0) {
    // end-of-tile: guarantee tile t+1 fully landed for ALL waves
    asm volatile("s_waitcnt vmcnt(%0)" :: "n"(VM) : "memory");
    __builtin_amdgcn_s_barrier();
    asm volatile("" ::: "memory");
  }
}

template<int NCOLS, bool F16OUT>
__global__ __launch_bounds__(512, 2)
void gemm_nt(const f16* __restrict__ A, const f16* __restrict__ Bt,
             const float* __restrict__ bias, void* __restrict__ Cout)
{
  __shared__ __align__(16) char lds[131072];
  char* ldsA = lds;
  char* ldsB = lds + 65536;

  const int tid = threadIdx.x;
  const int wave = tid >> 6, lane = tid & 63;
  const int rl = lane & 15, g = lane >> 4;
  const int wm = wave >> 2, wn = wave & 3;

  constexpr int NBN = NCOLS / 256;
  constexpr int NWG = 32 * NBN;          // grid size (M/256 = 32)
  const int bid = blockIdx.x;
  const int wgid = (bid & 7) * (NWG / 8) + (bid >> 3);   // XCD swizzle (NWG%8==0)
  const int bm = wgid / NBN, bn = wgid % NBN;
  const long row0 = (long)bm * 256, col0 = (long)bn * 256;

  // staging: per wave 2 segments of 1KB per matrix per tile (16 segs x 1KB = 16KB tile)
  const char* gA[2]; const char* gB[2]; char* dA[2]; char* dB[2];
#pragma unroll
  for (int l = 0; l < 2; ++l) {
    int seg = wave * 2 + l;
    int p = seg * 1024 + lane * 16;      // linear byte in [256][32] f16 tile
    int row = p >> 6, colB = p & 63;
    gA[l] = (const char*)A  + (row0 + row) * 2560 + colB;
    gB[l] = (const char*)Bt + (col0 + row) * 2560 + colB;
    dA[l] = ldsA + seg * 1024;
    dB[l] = ldsB + seg * 1024;
  }

  // fragment byte offsets within a 16KB tile (contiguous 1KB per 16-lane frag read)
  int offA[8], offB[4];
#pragma unroll
  for (int f = 0; f < 8; ++f) offA[f] = (wm * 128 + f * 16 + rl) * 64 + g * 16;
#pragma unroll
  for (int n = 0; n < 4; ++n) offB[n] = (wn * 64 + n * 16 + rl) * 64 + g * 16;

  f32x4 acc[8][4];
#pragma unroll
  for (int f = 0; f < 8; ++f)
#pragma unroll
    for (int n = 0; n < 4; ++n) acc[f][n] = (f32x4){0.f, 0.f, 0.f, 0.f};

  // prologue: stage tiles 0,1,2 (12 loads/wave); wait tile 0 (vmcnt<=8); barrier
#pragma unroll
  for (int t = 0; t < 3; ++t) {
#pragma unroll
    for (int l = 0; l < 2; ++l) gload_lds16(gA[l] + t * 64, dA[l] + t * 16384);
#pragma unroll
    for (int l = 0; l < 2; ++l) gload_lds16(gB[l] + t * 64, dB[l] + t * 16384);
  }
  asm volatile("s_waitcnt vmcnt(8)" ::: "memory");
  __builtin_amdgcn_s_barrier();
  asm volatile("" ::: "memory");

  // main loop: K = 1280 -> 40 tiles. t=0..35 unrolled x4 (const buf idx), then tail.
  for (int tt = 0; tt < 9; ++tt) {
    const int t = tt * 4;
    ktile<8, true>(t + 0, 3, gA, gB, dA, dB, ldsA + 0 * 16384, ldsB + 0 * 16384, offA, offB, acc);
    ktile<8, true>(t + 1, 0, gA, gB, dA, dB, ldsA + 1 * 16384, ldsB + 1 * 16384, offA, offB, acc);
    ktile<8, true>(t + 2, 1, gA, gB, dA, dB, ldsA + 2 * 16384, ldsB + 2 * 16384, offA, offB, acc);
    ktile<8, true>(t + 3, 2, gA, gB, dA, dB, ldsA + 3 * 16384, ldsB + 3 * 16384, offA, offB, acc);
  }
  ktile<8, true >(36, 3, gA, gB, dA, dB, ldsA + 0 * 16384, ldsB + 0 * 16384, offA, offB, acc); // stages 39
  ktile<4, false>(37, 0, gA, gB, dA, dB, ldsA + 1 * 16384, ldsB + 1 * 16384, offA, offB, acc);
  ktile<0, false>(38, 0, gA, gB, dA, dB, ldsA + 2 * 16384, ldsB + 2 * 16384, offA, offB, acc);
  ktile<-1, false>(39, 0, gA, gB, dA, dB, ldsA + 3 * 16384, ldsB + 3 * 16384, offA, offB, acc);

  // epilogue
#pragma unroll
  for (int f = 0; f < 8; ++f) {
#pragma unroll
    for (int n = 0; n < 4; ++n) {
      long c = col0 + wn * 64 + n * 16 + rl;
      float bv = bias[c];
#pragma unroll
      for (int r = 0; r < 4; ++r) {
        long rr = row0 + wm * 128 + f * 16 + g * 4 + r;
        float v = acc[f][n][r] + bv;
        if (F16OUT) ((f16*)Cout)[rr * NCOLS + c] = (f16)v;
        else        ((float*)Cout)[rr * NCOLS + c] = v;
      }
    }
  }
}

// ---------------- V transpose: qkv v-part -> vt[b*16+h][80][2048] ----------------
__global__ void k_vt(const f16* __restrict__ qkv, f16* __restrict__ vt) {
  __shared__ __align__(16) f16 T[128 * 136];
  int bid = blockIdx.x;              // 64 bh * 16 s-chunks
  int sc16 = bid & 15, bh = bid >> 4;
  int b = bh >> 4, h = bh & 15;
  int s0 = sc16 * 128;
  int t = threadIdx.x;
#pragma unroll
  for (int i = 0; i < 5; ++i) {
    int cid = i * 256 + t;           // 1280 = 128 s * 10 chunks
    int s = cid / 10, c = cid % 10;
    const f16* g = qkv + (size_t)((s0 + s) * 4 + b) * 3840 + 2560 + h * 80 + c * 8;
    f16x8 v = *(const f16x8*)g;
    int phys = c ^ ((s >> 3) & 7);
    *(f16x8*)(T + s * 136 + phys * 8) = v;
  }
  __syncthreads();
#pragma unroll
  for (int i = 0; i < 5; ++i) {
    int oid = i * 256 + t;           // 1280 = 80 hd * 16 s-subchunks
    int sc8 = oid & 15, hd = oid >> 4;
    f16x8 o;
#pragma unroll
    for (int j = 0; j < 8; ++j) {
      int row = sc8 * 8 + j;
      int phys = (hd >> 3) ^ (sc8 & 7);
      o[j] = T[row * 136 + phys * 8 + (hd & 7)];
    }
    *(f16x8*)(vt + (size_t)(bh * 80 + hd) * 2048 + s0 + sc8 * 8) = o;
  }
}

// ---------------- windowed attention ----------------
// block: (b, h, seg, qc) ; 512 threads = 8 waves * 16 queries
__global__ __launch_bounds__(512, 2)
void k_attn(const f16* __restrict__ qkv, const f16* __restrict__ vt,
            f16* __restrict__ ctx)
{
  __shared__ __align__(16) f16 sK[256 * 104];   // keys x (80 + zero-pad to 96, stride 104)
  __shared__ __align__(16) f16 sV[80 * 264];    // hd x 256 keys (stride 264)
  __shared__ __align__(16) f16 sP[128 * 72];    // q x 64-key chunk (stride 72)

  const int bid = blockIdx.x;                   // 1024
  const int qc = bid & 1, seg = (bid >> 1) & 7, h = (bid >> 4) & 15, b = bid >> 8;
  const int t = threadIdx.x;
  const int wave = t >> 6, lane = t & 63;
  const int s_key0 = seg * 256;

  // stage K (k-part of qkv, col base 1280 + h*80)
#pragma unroll
  for (int i = 0; i < 5; ++i) {
    int cid = i * 512 + t;                      // 2560 = 256 keys * 10 chunks
    int key = cid / 10, c = cid % 10;
    const f16* g = qkv + (size_t)((s_key0 + key) * 4 + b) * 3840 + 1280 + h * 80 + c * 8;
    *(f16x8*)(sK + key * 104 + c * 8) = *(const f16x8*)g;
  }
  { // zero cols 80..95
    int key = t >> 1, c = t & 1;
    *(f16x8*)(sK + key * 104 + 80 + c * 8) = zero8();
  }
  // stage V from vt
#pragma unroll
  for (int i = 0; i < 5; ++i) {
    int cid = i * 512 + t;                      // 2560 = 80 hd * 32 chunks
    int hd = cid >> 5, c = cid & 31;
    const f16* g = vt + (size_t)((b * 16 + h) * 80 + hd) * 2048 + s_key0 + c * 8;
    *(f16x8*)(sV + hd * 264 + c * 8) = *(const f16x8*)g;
  }

  // Q fragments direct from global (col base h*80); wave owns 16 queries
  const int q0 = s_key0 + qc * 128 + wave * 16;
  const int rl = lane & 15, g = lane >> 4;
  f16x8 qf[3];
  {
    const f16* gq = qkv + (size_t)((q0 + rl) * 4 + b) * 3840 + h * 80;
    qf[0] = *(const f16x8*)(gq + g * 8);
    qf[1] = *(const f16x8*)(gq + 32 + g * 8);
    if (g < 2) qf[2] = *(const f16x8*)(gq + 64 + g * 8);
    else       qf[2] = zero8();
  }
  __syncthreads();

  // QK^T : sc[nt] covers keys nt*16+(lane&15), rows g*4+r
  f32x4 sc[16];
#pragma unroll
  for (int nt = 0; nt < 16; ++nt) sc[nt] = (f32x4){0.f, 0.f, 0.f, 0.f};
#pragma unroll
  for (int nt = 0; nt < 16; ++nt) {
#pragma unroll
    for (int kk = 0; kk < 3; ++kk) {
      f16x8 bf = *(const f16x8*)(sK + (nt * 16 + rl) * 104 + kk * 32 + g * 8);
      sc[nt] = __builtin_amdgcn_mfma_f32_16x16x32_f16(qf[kk], bf, sc[nt], 0, 0, 0);
    }
  }

  // softmax (exact, full 256-key window in regs)
  const float scale = 0.11180339887498949f;
  float inv[4];
#pragma unroll
  for (int r = 0; r < 4; ++r) {
    float m = -1e30f;
#pragma unroll
    for (int nt = 0; nt < 16; ++nt) m = fmaxf(m, sc[nt][r]);
#pragma unroll
    for (int off = 8; off >= 1; off >>= 1) m = fmaxf(m, __shfl_xor(m, off));
    m *= scale;
    float sum = 0.f;
#pragma unroll
    for (int nt = 0; nt < 16; ++nt) {
      float p = __expf(sc[nt][r] * scale - m);
      sc[nt][r] = p;
      sum += p;
    }
#pragma unroll
    for (int off = 8; off >= 1; off >>= 1) sum += __shfl_xor(sum, off);
    inv[r] = 1.0f / sum;
  }

  // PV in 4 chunks of 64 keys; P bounced through wave-private sP rows
  f32x4 o[5];
#pragma unroll
  for (int nt = 0; nt < 5; ++nt) o[nt] = (f32x4){0.f, 0.f, 0.f, 0.f};
  const int prow0 = wave * 16;
  for (int ch = 0; ch < 4; ++ch) {
    __syncthreads();
#pragma unroll
    for (int f = 0; f < 4; ++f) {
      int nt = ch * 4 + f;
#pragma unroll
      for (int r = 0; r < 4; ++r)
        sP[(prow0 + g * 4 + r) * 72 + f * 16 + rl] = (f16)sc[nt][r];
    }
    __syncthreads();
#pragma unroll
    for (int kk = 0; kk < 2; ++kk) {
      f16x8 pa = *(const f16x8*)(sP + (prow0 + rl) * 72 + kk * 32 + g * 8);
#pragma unroll
      for (int nt = 0; nt < 5; ++nt) {
        f16x8 vb = *(const f16x8*)(sV + (nt * 16 + rl) * 264 + ch * 64 + kk * 32 + g * 8);
        o[nt] = __builtin_amdgcn_mfma_f32_16x16x32_f16(pa, vb, o[nt], 0, 0, 0);
      }
    }
  }

  // epilogue: normalize, store ctx fp16
#pragma unroll
  for (int nt = 0; nt < 5; ++nt) {
    int hd = nt * 16 + rl;
#pragma unroll
    for (int r = 0; r < 4; ++r) {
      long qrow = q0 + g * 4 + r;
      float v = o[nt][r] * inv[r];
      ctx[(qrow * 4 + b) * 1280 + h * 80 + hd] = (f16)v;
    }
  }
}

extern "C" void kernel_launch(void* const* d_in, const int* in_sizes, int n_in,
                              void* d_out, int out_size, void* d_ws, size_t ws_size,
                              hipStream_t stream)
{
  const float* x     = (const float*)d_in[0];
  const float* Wqkv  = (const float*)d_in[1];
  const float* bqkv  = (const float*)d_in[2];
  const float* Wproj = (const float*)d_in[3];
  const float* bproj = (const float*)d_in[4];

  char* ws = (char*)d_ws;
  f16* X16   = (f16*)(ws);                 // 20,971,520 B (reused as CTX16 after gemm1)
  f16* WQT   = (f16*)(ws + 20971520);      //  9,830,400 B
  f16* WPT   = (f16*)(ws + 30801920);      // 13,107,200 B
  f16* QKV16 = (f16*)(ws + 43909120);      // 62,914,560 B
  f16* VT    = (f16*)(ws + 106823680);     // 20,971,520 B  (total 127,795,200 B)
  f16* CTX16 = X16;                        // x dead after gemm1

  k_cvt_x<<<4096, 256, 0, stream>>>(x, X16, 8192 * 1280 / 4);
  k_cvt_w_t<<<40 * 120, 256, 0, stream>>>(Wqkv, WQT, 3840);
  k_cvt_w_t<<<40 * 160, 256, 0, stream>>>(Wproj, WPT, 5120);
  gemm_nt<3840, true ><<<480, 512, 0, stream>>>(X16, WQT, bqkv, QKV16);
  k_vt<<<1024, 256, 0, stream>>>(QKV16, VT);
  k_attn<<<1024, 512, 0, stream>>>(QKV16, VT, CTX16);
  gemm_nt<5120, false><<<640, 512, 0, stream>>>(CTX16, WPT, bproj, d_out);
}

// Round 3
// 281.541 us; speedup vs baseline: 1.0484x; 1.0484x over previous
//
#include <hip/hip_runtime.h>

typedef _Float16 f16;
typedef _Float16 f16x8 __attribute__((ext_vector_type(8)));
typedef _Float16 f16x4 __attribute__((ext_vector_type(4)));
typedef float    f32x4 __attribute__((ext_vector_type(4)));
typedef unsigned int u32t;

#define AS1 __attribute__((address_space(1)))
#define AS3 __attribute__((address_space(3)))

static __device__ __forceinline__ void gload_lds16(const void* g, void* l) {
  __builtin_amdgcn_global_load_lds((const AS1 u32t*)g, (AS3 u32t*)l, 16, 0, 0);
}

static __device__ __forceinline__ f16x8 zero8() {
  f16x8 z;
#pragma unroll
  for (int j = 0; j < 8; ++j) z[j] = (f16)0;
  return z;
}

// ---------------- convert x (fp32 -> fp16) ----------------
__global__ void k_cvt_x(const float* __restrict__ in, f16* __restrict__ out, int n4) {
  int stride = gridDim.x * blockDim.x;
  for (int i = blockIdx.x * blockDim.x + threadIdx.x; i < n4; i += stride) {
    float4 v = ((const float4*)in)[i];
    f16x4 o;
    o[0] = (f16)v.x; o[1] = (f16)v.y; o[2] = (f16)v.z; o[3] = (f16)v.w;
    ((f16x4*)out)[i] = o;
  }
}

// ---------------- convert + transpose W: [1280][N] f32 -> [N][1280] f16 ----------------
__global__ void k_cvt_w_t(const float* __restrict__ W, f16* __restrict__ Wt, int N) {
  __shared__ float T[32][33];
  int bk = blockIdx.x % 40;          // 1280/32
  int bn = blockIdx.x / 40;
  int k0 = bk * 32, n0 = bn * 32;
  int r = threadIdx.x >> 5;          // 0..7
  int c = threadIdx.x & 31;
#pragma unroll
  for (int i = 0; i < 4; ++i)
    T[r + i * 8][c] = W[(size_t)(k0 + r + i * 8) * N + n0 + c];
  __syncthreads();
#pragma unroll
  for (int i = 0; i < 4; ++i)
    Wt[(size_t)(n0 + r + i * 8) * 1280 + k0 + c] = (f16)T[c][r + i * 8];
}

// ================= 256x256 8-phase GEMM, BK=64, double-buffered =================
// C[M=8192, NCOLS] = A[8192,1280] * Bt[NCOLS,1280]^T + bias
// 512 thr = 8 waves (2M x 4N); per-wave 128x64 (8 m-frags x 4 n-frags); 16x16x32 MFMA.
// LDS 128KB: A bufs @ {0,32K}, B bufs @ {64K,96K}. Tile t (BK=64) -> buf t&1.
// Tile = [256 rows][128B] ; chunk-swizzle phys_chunk = chunk ^ (row&7) (zero-conflict,
// proven R0). Staging: linear LDS dest, pre-swizzled global source col.
// 4 phases/tile, quadrants (mh,nh) = (0,0),(0,1),(1,1),(1,0): A,B frags read ONCE.
// Per phase: reads | stage 1 half-tile (2 gloads) | barrier | lgkmcnt(0) | 16 MFMA | barrier.
// vmcnt(2) only at tile boundaries; stage pipeline 5 half-tiles ahead (race-free:
// every stage lands after its region's last read + an intervening barrier).

template<int NCOLS, bool F16OUT>
__global__ __launch_bounds__(512, 2)
void gemm_nt(const f16* __restrict__ A, const f16* __restrict__ Bt,
             const float* __restrict__ bias, void* __restrict__ Cout)
{
  __shared__ __align__(16) char lds[131072];
  const int tid = threadIdx.x;
  const int wave = tid >> 6, lane = tid & 63;
  const int rl = lane & 15, g = lane >> 4;
  const int wm = wave >> 2, wn = wave & 3;

  constexpr int NBN = NCOLS / 256;
  constexpr int NWG = 32 * NBN;
  const int bid = blockIdx.x;
  const int wgid = (bid & 7) * (NWG / 8) + (bid >> 3);   // XCD swizzle (NWG%8==0)
  const int bm = wgid / NBN, bn = wgid % NBN;
  const long row0 = (long)bm * 256, col0 = (long)bn * 256;

  // ---- staging: per-thread global src (pre-swizzled col), wave-uniform LDS dst ----
  const int srow = tid >> 3;                          // 0..63
  const int scol = ((tid & 7) ^ (srow & 7)) << 4;
  const char* gA = (const char*)A  + (row0 + srow) * 2560 + scol;
  const char* gB = (const char*)Bt + (col0 + srow) * 2560 + scol;
  char* const ldsw = lds + wave * 1024;               // + isB*65536 + buf*32768 + half*16384 (+8192 seg1)

  auto STAGE = [&](int isB, int buf, int half, int kb) {
    const char* s = (isB ? gB : gA) + half * (128 * 2560) + kb;
    char* d = ldsw + isB * 65536 + buf * 32768 + half * 16384;
    gload_lds16(s, d);
    gload_lds16(s + 64 * 2560, d + 8192);
  };

  // ---- fragment read offsets (swizzled) ----
  const int swz0 = ((0 + g) ^ (rl & 7)) << 4;         // kk=0 chunk
  const int swz1 = ((4 + g) ^ (rl & 7)) << 4;         // kk=1 chunk
  const int aoff = (wm * 128 + rl) << 7;
  const int boff = 65536 + ((wn * 64 + rl) << 7);

  auto LDA = [&](f16x8 (&af)[8], int buf, int mh) {
#pragma unroll
    for (int m = 0; m < 4; ++m) {
      const char* p = lds + buf * 32768 + aoff + (mh * 4 + m) * 2048;
      af[m * 2 + 0] = *(const f16x8*)(p + swz0);
      af[m * 2 + 1] = *(const f16x8*)(p + swz1);
    }
  };
  auto LDB = [&](f16x8 (&bf)[4], int buf, int nh) {
#pragma unroll
    for (int n = 0; n < 2; ++n) {
      const char* p = lds + buf * 32768 + boff + (nh * 2 + n) * 2048;
      bf[n * 2 + 0] = *(const f16x8*)(p + swz0);
      bf[n * 2 + 1] = *(const f16x8*)(p + swz1);
    }
  };

  f32x4 acc[8][4];
#pragma unroll
  for (int m = 0; m < 8; ++m)
#pragma unroll
    for (int n = 0; n < 4; ++n) acc[m][n] = (f32x4){0.f, 0.f, 0.f, 0.f};

  auto MM = [&](int mh, int nh, const f16x8 (&af)[8], const f16x8 (&bf)[4]) {
    __builtin_amdgcn_s_setprio(1);
#pragma unroll
    for (int m = 0; m < 4; ++m)
#pragma unroll
      for (int n = 0; n < 2; ++n)
#pragma unroll
        for (int kk = 0; kk < 2; ++kk)
          acc[mh * 4 + m][nh * 2 + n] = __builtin_amdgcn_mfma_f32_16x16x32_f16(
              af[m * 2 + kk], bf[n * 2 + kk], acc[mh * 4 + m][nh * 2 + n], 0, 0, 0);
    __builtin_amdgcn_s_setprio(0);
  };

#define BAR()    __builtin_amdgcn_s_barrier()
#define WLGKM()  asm volatile("s_waitcnt lgkmcnt(0)" ::: "memory")
#define WVM(N)   asm volatile("s_waitcnt vmcnt(" #N ")" ::: "memory")

  // One K-tile (4 phases). Stage slots: kb<0 => no stage. vmend: -1 none, else vmcnt(N).
  auto TILE = [&](int buf,
                  int s0b, int s0u, int s0h, int s0k,
                  int s1b, int s1u, int s1h, int s1k,
                  int s2b, int s2u, int s2h, int s2k,
                  int s3b, int s3u, int s3h, int s3k,
                  int vmend, bool endbar) {
    f16x8 af[8], bf0[4], bf1[4];
    // phase q0: quadrant (0,0)
    LDA(af, buf, 0); LDB(bf0, buf, 0);
    if (s0k >= 0) STAGE(s0b, s0u, s0h, s0k);
    BAR(); WLGKM(); MM(0, 0, af, bf0); BAR();
    // phase q1: quadrant (0,1)
    LDB(bf1, buf, 1);
    if (s1k >= 0) STAGE(s1b, s1u, s1h, s1k);
    BAR(); WLGKM(); MM(0, 1, af, bf1); BAR();
    // phase q2: quadrant (1,1)
    LDA(af, buf, 1);
    if (s2k >= 0) STAGE(s2b, s2u, s2h, s2k);
    BAR(); WLGKM(); MM(1, 1, af, bf1); BAR();
    // phase q3: quadrant (1,0) — no reads
    if (s3k >= 0) STAGE(s3b, s3u, s3h, s3k);
    BAR(); MM(1, 0, af, bf0);
    if (vmend == 2) WVM(2);
    else if (vmend == 0) WVM(0);
    if (endbar) BAR();
  };

  // ---- prologue: stage tile0 (4 halves) + tile1 Ah0 ----
  STAGE(0, 0, 0, 0); STAGE(0, 0, 1, 0); STAGE(1, 0, 0, 0); STAGE(1, 0, 1, 0);
  STAGE(0, 1, 0, 128);
  WVM(2); BAR();

  // ---- main: 9 iters x 2 tiles (tiles 0..17), then peel 18,19 ----
#pragma unroll 1
  for (int it = 0; it < 9; ++it) {
    const int kb = it * 256;
    TILE(0,
         0, 1, 1, kb + 128,   // tile 2it+1 Ah1
         1, 1, 0, kb + 128,   // tile 2it+1 Bh0
         1, 1, 1, kb + 128,   // tile 2it+1 Bh1
         0, 0, 0, kb + 256,   // tile 2it+2 Ah0
         2, true);
    TILE(1,
         0, 0, 1, kb + 256,   // tile 2it+2 Ah1
         1, 0, 0, kb + 256,   // tile 2it+2 Bh0
         1, 0, 1, kb + 256,   // tile 2it+2 Bh1
         0, 1, 0, kb + 384,   // tile 2it+3 Ah0
         2, true);
  }
  // tile 18 (buf0): stage tile19 halves; drain at end
  TILE(0,
       0, 1, 1, 2432,
       1, 1, 0, 2432,
       1, 1, 1, 2432,
       0, 0, 0, -1,
       0, true);
  // tile 19 (buf1): no stages, no trailing sync
  TILE(1, 0,0,0,-1, 0,0,0,-1, 0,0,0,-1, 0,0,0,-1, -1, false);

#undef BAR
#undef WLGKM
#undef WVM

  // ---- epilogue ----
#pragma unroll
  for (int m = 0; m < 8; ++m) {
#pragma unroll
    for (int n = 0; n < 4; ++n) {
      long c = col0 + wn * 64 + n * 16 + rl;
      float bv = bias[c];
#pragma unroll
      for (int r = 0; r < 4; ++r) {
        long rr = row0 + wm * 128 + m * 16 + g * 4 + r;
        float v = acc[m][n][r] + bv;
        if (F16OUT) ((f16*)Cout)[rr * NCOLS + c] = (f16)v;
        else        ((float*)Cout)[rr * NCOLS + c] = v;
      }
    }
  }
}

// ---------------- V transpose: qkv v-part -> vt[b*16+h][80][2048] ----------------
__global__ void k_vt(const f16* __restrict__ qkv, f16* __restrict__ vt) {
  __shared__ __align__(16) f16 T[128 * 136];
  int bid = blockIdx.x;              // 64 bh * 16 s-chunks
  int sc16 = bid & 15, bh = bid >> 4;
  int b = bh >> 4, h = bh & 15;
  int s0 = sc16 * 128;
  int t = threadIdx.x;
#pragma unroll
  for (int i = 0; i < 5; ++i) {
    int cid = i * 256 + t;           // 1280 = 128 s * 10 chunks
    int s = cid / 10, c = cid % 10;
    const f16* g = qkv + (size_t)((s0 + s) * 4 + b) * 3840 + 2560 + h * 80 + c * 8;
    f16x8 v = *(const f16x8*)g;
    int phys = c ^ ((s >> 3) & 7);
    *(f16x8*)(T + s * 136 + phys * 8) = v;
  }
  __syncthreads();
#pragma unroll
  for (int i = 0; i < 5; ++i) {
    int oid = i * 256 + t;           // 1280 = 80 hd * 16 s-subchunks
    int sc8 = oid & 15, hd = oid >> 4;
    f16x8 o;
#pragma unroll
    for (int j = 0; j < 8; ++j) {
      int row = sc8 * 8 + j;
      int phys = (hd >> 3) ^ (sc8 & 7);
      o[j] = T[row * 136 + phys * 8 + (hd & 7)];
    }
    *(f16x8*)(vt + (size_t)(bh * 80 + hd) * 2048 + s0 + sc8 * 8) = o;
  }
}

// ---------------- windowed attention ----------------
// block: (b, h, seg, qc) ; 512 threads = 8 waves * 16 queries
__global__ __launch_bounds__(512, 2)
void k_attn(const f16* __restrict__ qkv, const f16* __restrict__ vt,
            f16* __restrict__ ctx)
{
  __shared__ __align__(16) f16 sK[256 * 104];   // keys x (80 + zero-pad to 96, stride 104)
  __shared__ __align__(16) f16 sV[80 * 264];    // hd x 256 keys (stride 264)
  __shared__ __align__(16) f16 sP[128 * 72];    // q x 64-key chunk (stride 72)

  const int bid = blockIdx.x;                   // 1024
  const int qc = bid & 1, seg = (bid >> 1) & 7, h = (bid >> 4) & 15, b = bid >> 8;
  const int t = threadIdx.x;
  const int wave = t >> 6, lane = t & 63;
  const int s_key0 = seg * 256;

  // stage K (k-part of qkv, col base 1280 + h*80)
#pragma unroll
  for (int i = 0; i < 5; ++i) {
    int cid = i * 512 + t;                      // 2560 = 256 keys * 10 chunks
    int key = cid / 10, c = cid % 10;
    const f16* g = qkv + (size_t)((s_key0 + key) * 4 + b) * 3840 + 1280 + h * 80 + c * 8;
    *(f16x8*)(sK + key * 104 + c * 8) = *(const f16x8*)g;
  }
  { // zero cols 80..95
    int key = t >> 1, c = t & 1;
    *(f16x8*)(sK + key * 104 + 80 + c * 8) = zero8();
  }
  // stage V from vt
#pragma unroll
  for (int i = 0; i < 5; ++i) {
    int cid = i * 512 + t;                      // 2560 = 80 hd * 32 chunks
    int hd = cid >> 5, c = cid & 31;
    const f16* g = vt + (size_t)((b * 16 + h) * 80 + hd) * 2048 + s_key0 + c * 8;
    *(f16x8*)(sV + hd * 264 + c * 8) = *(const f16x8*)g;
  }

  // Q fragments direct from global (col base h*80); wave owns 16 queries
  const int q0 = s_key0 + qc * 128 + wave * 16;
  const int rl = lane & 15, g = lane >> 4;
  f16x8 qf[3];
  {
    const f16* gq = qkv + (size_t)((q0 + rl) * 4 + b) * 3840 + h * 80;
    qf[0] = *(const f16x8*)(gq + g * 8);
    qf[1] = *(const f16x8*)(gq + 32 + g * 8);
    if (g < 2) qf[2] = *(const f16x8*)(gq + 64 + g * 8);
    else       qf[2] = zero8();
  }
  __syncthreads();

  // QK^T : sc[nt] covers keys nt*16+(lane&15), rows g*4+r
  f32x4 sc[16];
#pragma unroll
  for (int nt = 0; nt < 16; ++nt) sc[nt] = (f32x4){0.f, 0.f, 0.f, 0.f};
#pragma unroll
  for (int nt = 0; nt < 16; ++nt) {
#pragma unroll
    for (int kk = 0; kk < 3; ++kk) {
      f16x8 bf = *(const f16x8*)(sK + (nt * 16 + rl) * 104 + kk * 32 + g * 8);
      sc[nt] = __builtin_amdgcn_mfma_f32_16x16x32_f16(qf[kk], bf, sc[nt], 0, 0, 0);
    }
  }

  // softmax (exact, full 256-key window in regs)
  const float scale = 0.11180339887498949f;
  float inv[4];
#pragma unroll
  for (int r = 0; r < 4; ++r) {
    float m = -1e30f;
#pragma unroll
    for (int nt = 0; nt < 16; ++nt) m = fmaxf(m, sc[nt][r]);
#pragma unroll
    for (int off = 8; off >= 1; off >>= 1) m = fmaxf(m, __shfl_xor(m, off));
    m *= scale;
    float sum = 0.f;
#pragma unroll
    for (int nt = 0; nt < 16; ++nt) {
      float p = __expf(sc[nt][r] * scale - m);
      sc[nt][r] = p;
      sum += p;
    }
#pragma unroll
    for (int off = 8; off >= 1; off >>= 1) sum += __shfl_xor(sum, off);
    inv[r] = 1.0f / sum;
  }

  // PV in 4 chunks of 64 keys; P bounced through wave-private sP rows
  f32x4 o[5];
#pragma unroll
  for (int nt = 0; nt < 5; ++nt) o[nt] = (f32x4){0.f, 0.f, 0.f, 0.f};
  const int prow0 = wave * 16;
  for (int ch = 0; ch < 4; ++ch) {
    __syncthreads();
#pragma unroll
    for (int f = 0; f < 4; ++f) {
      int nt = ch * 4 + f;
#pragma unroll
      for (int r = 0; r < 4; ++r)
        sP[(prow0 + g * 4 + r) * 72 + f * 16 + rl] = (f16)sc[nt][r];
    }
    __syncthreads();
#pragma unroll
    for (int kk = 0; kk < 2; ++kk) {
      f16x8 pa = *(const f16x8*)(sP + (prow0 + rl) * 72 + kk * 32 + g * 8);
#pragma unroll
      for (int nt = 0; nt < 5; ++nt) {
        f16x8 vb = *(const f16x8*)(sV + (nt * 16 + rl) * 264 + ch * 64 + kk * 32 + g * 8);
        o[nt] = __builtin_amdgcn_mfma_f32_16x16x32_f16(pa, vb, o[nt], 0, 0, 0);
      }
    }
  }

  // epilogue: normalize, store ctx fp16
#pragma unroll
  for (int nt = 0; nt < 5; ++nt) {
    int hd = nt * 16 + rl;
#pragma unroll
    for (int r = 0; r < 4; ++r) {
      long qrow = q0 + g * 4 + r;
      float v = o[nt][r] * inv[r];
      ctx[(qrow * 4 + b) * 1280 + h * 80 + hd] = (f16)v;
    }
  }
}

extern "C" void kernel_launch(void* const* d_in, const int* in_sizes, int n_in,
                              void* d_out, int out_size, void* d_ws, size_t ws_size,
                              hipStream_t stream)
{
  const float* x     = (const float*)d_in[0];
  const float* Wqkv  = (const float*)d_in[1];
  const float* bqkv  = (const float*)d_in[2];
  const float* Wproj = (const float*)d_in[3];
  const float* bproj = (const float*)d_in[4];

  char* ws = (char*)d_ws;
  f16* X16   = (f16*)(ws);                 // 20,971,520 B (reused as CTX16 after gemm1)
  f16* WQT   = (f16*)(ws + 20971520);      //  9,830,400 B
  f16* WPT   = (f16*)(ws + 30801920);      // 13,107,200 B
  f16* QKV16 = (f16*)(ws + 43909120);      // 62,914,560 B
  f16* VT    = (f16*)(ws + 106823680);     // 20,971,520 B  (total 127,795,200 B)
  f16* CTX16 = X16;                        // x dead after gemm1

  k_cvt_x<<<4096, 256, 0, stream>>>(x, X16, 8192 * 1280 / 4);
  k_cvt_w_t<<<40 * 120, 256, 0, stream>>>(Wqkv, WQT, 3840);
  k_cvt_w_t<<<40 * 160, 256, 0, stream>>>(Wproj, WPT, 5120);
  gemm_nt<3840, true ><<<480, 512, 0, stream>>>(X16, WQT, bqkv, QKV16);
  k_vt<<<1024, 256, 0, stream>>>(QKV16, VT);
  k_attn<<<1024, 512, 0, stream>>>(QKV16, VT, CTX16);
  gemm_nt<5120, false><<<640, 512, 0, stream>>>(CTX16, WPT, bproj, d_out);
}